// Round 1
// 6125.235 us; speedup vs baseline: 1.0393x; 1.0393x over previous
//
#include <hip/hip_runtime.h>
#include <hip/hip_bf16.h>

#define T_TOTAL 1024
#define BATCH   64
#define HID     512

__device__ __forceinline__ float fast_sigmoid(float x) {
    return 1.f / (1.f + __expf(-x));
}
__device__ __forceinline__ float fast_tanh(float x) {
    float ax = fabsf(x);
    float e  = __expf(-2.f * ax);
    float t  = (1.f - e) / (1.f + e);
    return copysignf(t, x);
}

// ---------------------------------------------------------------------------
// GEMM: C[m,n] = sum_k A[rowg(m),k] * W[n,k] + bias[n]
// A row-major [*, K], W row-major [N, K] (i.e. computes A @ W^T + bias).
// ---------------------------------------------------------------------------
template<int BM, int BN, int TM, int TN>
__global__ __launch_bounds__(256, 2)
void gemm_bt_k(const float* __restrict__ A, const float* __restrict__ W,
               const float* __restrict__ bias, float* __restrict__ C,
               int K, int T, int Tc, int t0, int N)
{
    constexpr int BK = 16;
    constexpr int WSTR = BN + (BN / 32) * 4;
    static_assert(BM / TM == 16 && BN / TN == 16, "256 threads required");
    __shared__ float As[BK][BM + 4];
    __shared__ float Ws[BK][WSTR];

    const int tid = threadIdx.x;
    const int tx  = tid & 15;
    const int ty  = tid >> 4;
    const int m0  = blockIdx.y * BM;
    const int n0  = blockIdx.x * BN;
    const int nA  = tx * TN;
    const int nsw = nA + ((nA >> 5) << 2);

    float acc[TM][TN];
#pragma unroll
    for (int i = 0; i < TM; ++i)
#pragma unroll
        for (int j = 0; j < TN; ++j) acc[i][j] = 0.f;

    for (int k0 = 0; k0 < K; k0 += BK) {
#pragma unroll
        for (int i = 0; i < (BM * BK) / 1024; ++i) {
            int id = tid + (i << 8);
            int m  = id >> 2;
            int kq = (id & 3) << 2;
            int mloc = m0 + m;
            int rowg = (mloc / Tc) * T + t0 + (mloc % Tc);
            const float4 v = *reinterpret_cast<const float4*>(A + (size_t)rowg * K + k0 + kq);
            As[kq + 0][m] = v.x; As[kq + 1][m] = v.y;
            As[kq + 2][m] = v.z; As[kq + 3][m] = v.w;
        }
#pragma unroll
        for (int i = 0; i < (BN * BK) / 1024; ++i) {
            int id = tid + (i << 8);
            int n  = id >> 2;
            int kq = (id & 3) << 2;
            const float4 v = *reinterpret_cast<const float4*>(W + (size_t)(n0 + n) * K + k0 + kq);
            int np = n + ((n >> 5) << 2);
            Ws[kq + 0][np] = v.x; Ws[kq + 1][np] = v.y;
            Ws[kq + 2][np] = v.z; Ws[kq + 3][np] = v.w;
        }
        __syncthreads();
#pragma unroll
        for (int k = 0; k < BK; ++k) {
            float a[TM], b[TN];
#pragma unroll
            for (int i = 0; i < TM; i += 4)
                *reinterpret_cast<float4*>(&a[i]) =
                    *reinterpret_cast<const float4*>(&As[k][ty * TM + i]);
#pragma unroll
            for (int j = 0; j < TN; j += 4)
                *reinterpret_cast<float4*>(&b[j]) =
                    *reinterpret_cast<const float4*>(&Ws[k][nsw + j]);
#pragma unroll
            for (int i = 0; i < TM; ++i)
#pragma unroll
                for (int j = 0; j < TN; ++j)
                    acc[i][j] = fmaf(a[i], b[j], acc[i][j]);
        }
        __syncthreads();
    }
#pragma unroll
    for (int i = 0; i < TM; ++i) {
        const size_t crow = (size_t)(m0 + ty * TM + i) * N + n0 + nA;
#pragma unroll
        for (int j = 0; j < TN; j += 4) {
            float4 bv = *reinterpret_cast<const float4*>(bias + n0 + nA + j);
            float4 v;
            v.x = acc[i][j + 0] + bv.x; v.y = acc[i][j + 1] + bv.y;
            v.z = acc[i][j + 2] + bv.z; v.w = acc[i][j + 3] + bv.w;
            *reinterpret_cast<float4*>(C + crow + j) = v;
        }
    }
}

// ---------------------------------------------------------------------------
// Persistent GRU scan (one T-chunk of one layer) — R11.
// R10 skeleton, poll loop DE-BRANCHED. The old poll had per-lane predicated
// atomic loads + a pend-mask state machine + divergent staged LDS writes:
// ~50 VALU/SALU + 4 exec-mask round trips per iteration, spinning in all 8
// waves for the whole publish round-trip window (~1.5us). That issue
// pressure was ~1/3 of VALUBusy and stole slots from the co-resident
// wave's MAC. New poll: unconditional dual load, branch-free per-lane ok,
// wave-uniform exit via __all, stage once after. Safe because re-loading an
// already-tagged word returns the same value (slot can only be overwritten
// at step t+2, after this consumer's t+1 barrier) and the producer always
// publishes all 128 words. s_sleep dropped (load latency paces the loop).
// Everything else identical to R10: per-wave dataflow pipelining, ONE
// barrier/step, part[]/h_lds double-buffered by parity, merged reduce+gates,
// fire-and-forget tagged publish.
// ---------------------------------------------------------------------------
__global__ __launch_bounds__(512, 2)
void gru_scan(const float* __restrict__ xg,    // chunk-local [64][Tc][1536]
              const float* __restrict__ w_hh,  // [1536][512]
              const float* __restrict__ b_hh,  // [1536]
              float* __restrict__ y,           // [64][1024][512]
              unsigned long long* __restrict__ hbuf, // [32 grp][2 slot][2 b][512]
              int t0, int Tc, int tagbase)
{
    const int tid = threadIdx.x;
    const int grp = blockIdx.x & 31;      // 8 blocks of a group
    const int os  = blockIdx.x >> 5;      // output slice 0..7
    const int D0  = os << 6;              // 64 h-dims per block
    const int d   = tid & 63;             // lane
    const int kc  = tid >> 6;             // wave index == its K-chunk
    const int bg  = grp << 1;             // 2 batch rows per group

    __shared__ float h_lds[2][1024];      // [slot][b*512 + D]
    __shared__ float part[2][8 * 392];    // [slot][kc][g*128 + b*64 + d]

    // persistent weights: w4[g][j] = w_hh[g*512+D0+d][kc*64 + 4j ..]
    float4 w4[3][16];
#pragma unroll
    for (int g = 0; g < 3; ++g) {
        const float* wr = w_hh + (size_t)(g * 512 + D0 + d) * 512 + kc * 64;
#pragma unroll
        for (int j = 0; j < 16; ++j)
            w4[g][j] = *reinterpret_cast<const float4*>(wr + (j << 2));
    }
    // gate-thread biases (merged reduce+gates)
    float bias_r = 0.f, bias_z = 0.f, bias_n = 0.f;
    if (tid < 128) {
        bias_r = b_hh[       D0 + d];
        bias_z = b_hh[ 512 + D0 + d];
        bias_n = b_hh[1024 + D0 + d];
    }
    const int b_loc = tid >> 6;           // gate threads (tid<128): row 0..1

    for (int tl = 0; tl < Tc; ++tl) {
        const int tg = t0 + tl;
        float* hl = h_lds[tl & 1];
        float* pt = part[tl & 1];

        // gate threads prefetch this step's xg early (hidden behind poll)
        float xr = 0.f, xz = 0.f, xn = 0.f;
        if (tid < 128) {
            const size_t rowo = ((size_t)(bg + b_loc) * Tc + tl) * 1536 + D0 + d;
            xr = xg[rowo];
            xz = xg[rowo + 512];
            xn = xg[rowo + 1024];
        }

        // per-wave staging: wave kc polls ONLY publisher kc's 128 words.
        // Branch-free body: both loads unconditional, wave-uniform exit.
        if (tg == 0) {
            hl[      kc * 64 + d] = 0.f;
            hl[512 + kc * 64 + d] = 0.f;
        } else {
            const unsigned long long* hsrc =
                hbuf + (size_t)(grp * 2 + ((tg - 1) & 1)) * 1024 + kc * 64;
            const unsigned int tagexp = (unsigned int)(tagbase + tl - 1);
            unsigned long long v0, v1;
            for (;;) {
                v0 = __hip_atomic_load(hsrc + d,
                        __ATOMIC_RELAXED, __HIP_MEMORY_SCOPE_AGENT);
                v1 = __hip_atomic_load(hsrc + 512 + d,
                        __ATOMIC_RELAXED, __HIP_MEMORY_SCOPE_AGENT);
                const int ok = (int)(((unsigned int)(v0 >> 32) == tagexp) &
                                     ((unsigned int)(v1 >> 32) == tagexp));
                if (__all(ok)) break;
            }
            union { unsigned int u; float f; } c0, c1;
            c0.u = (unsigned int)v0;
            c1.u = (unsigned int)v1;
            hl[      kc * 64 + d] = c0.f;
            hl[512 + kc * 64 + d] = c1.f;
        }
        // wave-local LDS RAW: drain lgkmcnt before the broadcast reads
        __builtin_amdgcn_s_waitcnt(0xC07F);   // lgkmcnt(0) only

        // register MAC over this wave's 64-wide K chunk (broadcast reads)
        float acc[3][2];
#pragma unroll
        for (int g = 0; g < 3; ++g) { acc[g][0] = 0.f; acc[g][1] = 0.f; }
        const float* hb = hl + kc * 64;
#pragma unroll
        for (int j = 0; j < 16; ++j) {
            const float4 h0 = *reinterpret_cast<const float4*>(hb + (j << 2));
            const float4 h1 = *reinterpret_cast<const float4*>(hb + 512 + (j << 2));
#pragma unroll
            for (int g = 0; g < 3; ++g) {
                const float4 wv = w4[g][j];
                acc[g][0] = fmaf(wv.x, h0.x, acc[g][0]);
                acc[g][0] = fmaf(wv.y, h0.y, acc[g][0]);
                acc[g][0] = fmaf(wv.z, h0.z, acc[g][0]);
                acc[g][0] = fmaf(wv.w, h0.w, acc[g][0]);
                acc[g][1] = fmaf(wv.x, h1.x, acc[g][1]);
                acc[g][1] = fmaf(wv.y, h1.y, acc[g][1]);
                acc[g][1] = fmaf(wv.z, h1.z, acc[g][1]);
                acc[g][1] = fmaf(wv.w, h1.w, acc[g][1]);
            }
        }
        {
            float* pp = pt + kc * 392 + d;
#pragma unroll
            for (int g = 0; g < 3; ++g) {
                pp[g * 128]      = acc[g][0];
                pp[g * 128 + 64] = acc[g][1];
            }
        }
        __syncthreads();   // the ONLY barrier per step

        // merged reduce + gates + tagged publish (fire-and-forget).
        // FP order identical to R8-R10: bias first, then q ascending.
        if (tid < 128) {
            float sr = bias_r, sz = bias_z, sn = bias_n;
#pragma unroll
            for (int q = 0; q < 8; ++q) {
                sr += pt[q * 392 +       tid];
                sz += pt[q * 392 + 128 + tid];
                sn += pt[q * 392 + 256 + tid];
            }
            const int D = D0 + d;
            const float hp = hl[b_loc * 512 + D];
            const float r  = fast_sigmoid(xr + sr);
            const float z  = fast_sigmoid(xz + sz);
            const float nv = fast_tanh(xn + r * sn);
            const float h  = (1.f - z) * nv + z * hp;
            union { float f; unsigned int u; } cv; cv.f = h;
            const unsigned long long pk =
                ((unsigned long long)(unsigned int)(tagbase + tl) << 32) | cv.u;
            unsigned long long* hdst =
                hbuf + (size_t)(grp * 2 + (tg & 1)) * 1024 + b_loc * 512 + D;
            __hip_atomic_store(hdst, pk, __ATOMIC_RELAXED,
                               __HIP_MEMORY_SCOPE_AGENT);
            y[((size_t)(bg + b_loc) * T_TOTAL + tg) * HID + D] = h;
        }
        // no trailing barrier: h_lds/part are double-buffered by step parity.
    }
}

// ---------------------------------------------------------------------------
extern "C" void kernel_launch(void* const* d_in, const int* in_sizes, int n_in,
                              void* d_out, int out_size, void* d_ws, size_t ws_size,
                              hipStream_t stream)
{
    const float* x       = (const float*)d_in[0];
    const float* w_ih[2] = {(const float*)d_in[1], (const float*)d_in[5]};
    const float* w_hh[2] = {(const float*)d_in[2], (const float*)d_in[6]};
    const float* b_ih[2] = {(const float*)d_in[3], (const float*)d_in[7]};
    const float* b_hh[2] = {(const float*)d_in[4], (const float*)d_in[8]};
    const float* fc_w    = (const float*)d_in[9];
    const float* fc_b    = (const float*)d_in[10];
    float* out = (float*)d_out;

    const size_t Y_BYTES = (size_t)BATCH * T_TOTAL * HID * 4;   // 128 MiB
    const size_t H_BYTES = (size_t)32 * 2 * 2 * 512 * 8;        // 512 KiB (u64)
    int Tc = 256;
    while (Tc > 32) {
        size_t need = (size_t)BATCH * Tc * 1536 * 4 + Y_BYTES + H_BYTES;
        if (need <= ws_size) break;
        Tc >>= 1;
    }

    char* p = (char*)d_ws;
    float* xg_buf = (float*)p;                 p += (size_t)BATCH * Tc * 1536 * 4;
    float* y_buf  = (float*)p;                 p += Y_BYTES;
    unsigned long long* hbuf = (unsigned long long*)p;

    const int nchunks = T_TOTAL / Tc;
    for (int L = 0; L < 2; ++L) {
        const float* A = L ? y_buf : x;
        const int K    = L ? HID : 64;
        for (int c = 0; c < nchunks; ++c) {
            dim3 g1(1536 / 128, (BATCH * Tc) / 128);
            gemm_bt_k<128, 128, 8, 8><<<g1, 256, 0, stream>>>(
                A, w_ih[L], b_ih[L], xg_buf, K, T_TOTAL, Tc, c * Tc, 1536);
            gru_scan<<<256, 512, 0, stream>>>(
                xg_buf, w_hh[L], b_hh[L], y_buf, hbuf,
                c * Tc, Tc, (L << 11) + c * Tc);
        }
    }
    dim3 g2(64 / 64, (BATCH * T_TOTAL) / 128);
    gemm_bt_k<128, 64, 8, 4><<<g2, 256, 0, stream>>>(
        y_buf, fc_w, fc_b, out, HID, BATCH * T_TOTAL, BATCH * T_TOTAL, 0, 64);
}